// Round 1
// baseline (707.128 us; speedup 1.0000x reference)
//
#include <hip/hip_runtime.h>

// ---------------------------------------------------------------------------
// DeepFFM: out[b] = X[b]·w1 + b0 + x^T triu(S,1) x + MLP(X[b])
//   S[i,j] = sum_k nfk[i, f2f[j], k] * nfk[j, f2f[i], k]
// Sizes: BATCH=4096, F=1000, FIELDS=39, K=40, layers 1024/512/256 -> 1
// Round 1: exact fp32 baseline. GEMMs on vector ALU (no fp32 MFMA on CDNA4).
// ---------------------------------------------------------------------------

#define BATCH   4096
#define FSZ     1000
#define NFIELDS 39
#define KDIM    40

// ---------------------------------------------------------------------------
// Kernel 1: M[i][j] = (j > i) ? dot(nfk[i, f2f[j], :], nfk[j, f2f[i], :]) : 0
// grid (4, 1000) x 256
// ---------------------------------------------------------------------------
__global__ __launch_bounds__(256) void compute_M_kernel(
    const float* __restrict__ nfk, const int* __restrict__ f2f,
    float* __restrict__ M)
{
  int i = blockIdx.y;
  int j = blockIdx.x * 256 + threadIdx.x;
  if (j >= FSZ) return;
  float s = 0.f;
  if (j > i) {
    int fi = f2f[i], fj = f2f[j];
    // rows are 40 floats = 160 B, 16B-aligned -> float4 loads are legal
    const float4* p = (const float4*)(nfk + ((size_t)i * NFIELDS + fj) * KDIM);
    const float4* q = (const float4*)(nfk + ((size_t)j * NFIELDS + fi) * KDIM);
    #pragma unroll
    for (int k = 0; k < KDIM / 4; ++k) {
      float4 a = p[k], b = q[k];
      s += a.x * b.x + a.y * b.y + a.z * b.z + a.w * b.w;
    }
  }
  M[(size_t)i * FSZ + j] = s;
}

// ---------------------------------------------------------------------------
// Kernel 2: generic fp32 GEMM  C = [relu]( A(MxK) * B(KxN) + bias )
// 128x128 tile, BK=8, 256 threads, 8x8 acc/thread.
// M assumed multiple of 128 (always 4096 here); N guarded; K multiple of 8.
// ---------------------------------------------------------------------------
__global__ __launch_bounds__(256) void gemm_f32_kernel(
    const float* __restrict__ A, const float* __restrict__ B,
    const float* __restrict__ bias, float* __restrict__ C,
    int N, int K, int do_relu)
{
  __shared__ float As[8][128];
  __shared__ float Bs[8][128];
  const int tid  = threadIdx.x;
  const int tx   = tid & 15;     // 16 col groups of 8
  const int ty   = tid >> 4;     // 16 row groups of 8
  const int row0 = blockIdx.y * 128;
  const int col0 = blockIdx.x * 128;

  const int ar  = tid >> 1;        // 0..127 : A row within tile
  const int acv = (tid & 1) * 4;   // 0 or 4 : A col (k) within tile
  const int bk  = tid >> 5;        // 0..7   : B row (k) within tile
  const int bcv = (tid & 31) * 4;  // 0..124 : B col within tile

  float acc[8][8];
  #pragma unroll
  for (int i = 0; i < 8; ++i)
    #pragma unroll
    for (int j = 0; j < 8; ++j) acc[i][j] = 0.f;

  for (int k0 = 0; k0 < K; k0 += 8) {
    __syncthreads();
    {
      // A tile: 128 rows x 8 k. K%4==0 for all calls -> aligned float4.
      float4 v = *(const float4*)(A + (size_t)(row0 + ar) * K + (k0 + acv));
      As[acv + 0][ar] = v.x; As[acv + 1][ar] = v.y;
      As[acv + 2][ar] = v.z; As[acv + 3][ar] = v.w;
    }
    {
      // B tile: 8 k x 128 cols, guarded on N
      int c = col0 + bcv;
      const float* brow = B + (size_t)(k0 + bk) * N;
      float4 v = make_float4(0.f, 0.f, 0.f, 0.f);
      if (c + 3 < N) {
        v = *(const float4*)(brow + c);
      } else {
        if (c + 0 < N) v.x = brow[c + 0];
        if (c + 1 < N) v.y = brow[c + 1];
        if (c + 2 < N) v.z = brow[c + 2];
      }
      *(float4*)&Bs[bk][bcv] = v;
    }
    __syncthreads();
    #pragma unroll
    for (int k = 0; k < 8; ++k) {
      float a[8], bb[8];
      *(float4*)&a[0]  = *(const float4*)&As[k][ty * 8];
      *(float4*)&a[4]  = *(const float4*)&As[k][ty * 8 + 4];
      *(float4*)&bb[0] = *(const float4*)&Bs[k][tx * 8];
      *(float4*)&bb[4] = *(const float4*)&Bs[k][tx * 8 + 4];
      #pragma unroll
      for (int i = 0; i < 8; ++i)
        #pragma unroll
        for (int j = 0; j < 8; ++j)
          acc[i][j] = fmaf(a[i], bb[j], acc[i][j]);
    }
  }

  #pragma unroll
  for (int i = 0; i < 8; ++i) {
    int r = row0 + ty * 8 + i;
    float* crow = C + (size_t)r * N;
    #pragma unroll
    for (int j = 0; j < 8; ++j) {
      int c = col0 + tx * 8 + j;
      if (c < N) {
        float v = acc[i][j];
        if (bias) v += bias[c];
        if (do_relu) v = fmaxf(v, 0.f);
        crow[c] = v;
      }
    }
  }
}

// ---------------------------------------------------------------------------
// Kernel 3: out[b] = X[b]·w1 + b0 + sum_j T[b][j] * X[b][j]
// one block (256 thr) per batch row
// ---------------------------------------------------------------------------
__global__ __launch_bounds__(256) void rowdot_kernel(
    const float* __restrict__ X, const float* __restrict__ w1,
    const float* __restrict__ bsc, const float* __restrict__ T,
    float* __restrict__ out)
{
  __shared__ float sm1[4], sm2[4];
  int b = blockIdx.x;
  const float* xr = X + (size_t)b * FSZ;
  const float* tr = T + (size_t)b * FSZ;
  float pi = 0.f, pl = 0.f;
  for (int j = threadIdx.x; j < FSZ; j += 256) {
    float x = xr[j];
    pi += tr[j] * x;
    pl += x * w1[j];
  }
  #pragma unroll
  for (int o = 32; o; o >>= 1) {
    pi += __shfl_down(pi, o, 64);
    pl += __shfl_down(pl, o, 64);
  }
  int lane = threadIdx.x & 63, w = threadIdx.x >> 6;
  if (!lane) { sm1[w] = pi; sm2[w] = pl; }
  __syncthreads();
  if (!threadIdx.x)
    out[b] = (sm2[0] + sm2[1] + sm2[2] + sm2[3]) + bsc[0]
           + (sm1[0] + sm1[1] + sm1[2] + sm1[3]);
}

// ---------------------------------------------------------------------------
// Kernel 4: out[b] += h2[b]·outW + outB   (256 cols, one block per row)
// ---------------------------------------------------------------------------
__global__ __launch_bounds__(256) void outdot_kernel(
    const float* __restrict__ h2, const float* __restrict__ oW,
    const float* __restrict__ oB, float* __restrict__ out)
{
  __shared__ float sm[4];
  int b = blockIdx.x;
  float p = h2[(size_t)b * 256 + threadIdx.x] * oW[threadIdx.x];
  #pragma unroll
  for (int o = 32; o; o >>= 1) p += __shfl_down(p, o, 64);
  int lane = threadIdx.x & 63, w = threadIdx.x >> 6;
  if (!lane) sm[w] = p;
  __syncthreads();
  if (!threadIdx.x) out[b] += sm[0] + sm[1] + sm[2] + sm[3] + oB[0];
}

// ---------------------------------------------------------------------------
extern "C" void kernel_launch(void* const* d_in, const int* in_sizes, int n_in,
                              void* d_out, int out_size, void* d_ws, size_t ws_size,
                              hipStream_t stream) {
  const float* X   = (const float*)d_in[0];
  const float* w1  = (const float*)d_in[1];
  const float* bsc = (const float*)d_in[2];
  const float* nfk = (const float*)d_in[3];
  const int*   f2f = (const int*)d_in[4];
  const float* W0  = (const float*)d_in[5];
  const float* B0  = (const float*)d_in[6];
  const float* W1  = (const float*)d_in[7];
  const float* B1  = (const float*)d_in[8];
  const float* W2  = (const float*)d_in[9];
  const float* B2  = (const float*)d_in[10];
  const float* oW  = (const float*)d_in[11];
  const float* oB  = (const float*)d_in[12];
  float* out = (float*)d_out;

  char* ws = (char*)d_ws;
  // region R1 holds T (4096x1000) first, then is reused for h0 (4096x1024)
  float* R1 = (float*)(ws);                      // 16,777,216 B
  float* Mm = (float*)(ws + 16777216);           //  4,000,000 B
  float* h1 = (float*)(ws + 20777216);           //  8,388,608 B
  float* h2 = (float*)(ws + 29165824);           //  4,194,304 B
  // total 33,360,128 B

  // 1) S / M matrix
  compute_M_kernel<<<dim3(4, FSZ), 256, 0, stream>>>(nfk, f2f, Mm);

  // 2) T = X @ M   (4096 x 1000, K=1000)
  gemm_f32_kernel<<<dim3(8, 32), 256, 0, stream>>>(X, Mm, nullptr, R1,
                                                   FSZ, FSZ, 0);

  // 3) out = linear + interaction
  rowdot_kernel<<<BATCH, 256, 0, stream>>>(X, w1, bsc, R1, out);

  // 4) h0 = relu(X @ W0 + B0)    (4096 x 1024, K=1000) -> overwrite R1
  gemm_f32_kernel<<<dim3(8, 32), 256, 0, stream>>>(X, W0, B0, R1,
                                                   1024, FSZ, 1);
  // 5) h1 = relu(h0 @ W1 + B1)   (4096 x 512, K=1024)
  gemm_f32_kernel<<<dim3(4, 32), 256, 0, stream>>>(R1, W1, B1, h1,
                                                   512, 1024, 1);
  // 6) h2 = relu(h1 @ W2 + B2)   (4096 x 256, K=512)
  gemm_f32_kernel<<<dim3(2, 32), 256, 0, stream>>>(h1, W2, B2, h2,
                                                   256, 512, 1);
  // 7) out += h2 @ outW + outB
  outdot_kernel<<<BATCH, 256, 0, stream>>>(h2, oW, oB, out);
}

// Round 2
// 120.829 us; speedup vs baseline: 5.8523x; 5.8523x over previous
//
#include <hip/hip_runtime.h>

// ---------------------------------------------------------------------------
// DeepFFM round 2: bf16 MFMA GEMMs (fp32 accumulate), fused bias+relu epilogue.
//   out[b] = X[b]·w1 + b0 + x^T triu(S,1) x + MLP(X[b])
// All GEMMs: A (M x K bf16, row-major), Bt (N x K bf16, row-major = B^T),
// K padded to mult of 64 with zeros, N mult of 128, M=4096.
// ---------------------------------------------------------------------------

#define BATCH   4096
#define FSZ     1000
#define NFIELDS 39
#define KDIM    40

typedef __attribute__((ext_vector_type(8))) short short8v;  // 8 x bf16
typedef __attribute__((ext_vector_type(4))) float f32x4;

__device__ __forceinline__ short f2bf(float f) {
  unsigned u = __builtin_bit_cast(unsigned, f);
  u += 0x7fff + ((u >> 16) & 1);   // round-to-nearest-even (finite data)
  return (short)(u >> 16);
}

typedef const __attribute__((address_space(1))) unsigned int* gas_ptr;
typedef __attribute__((address_space(3))) unsigned int* las_ptr;
__device__ __forceinline__ void gload16(const void* g, void* l) {
  // async global->LDS, 16B/lane; LDS dest = wave-uniform base + lane*16
  __builtin_amdgcn_global_load_lds((gas_ptr)g, (las_ptr)l, 16, 0, 0);
}

// ---------------------------------------------------------------------------
// X (4096 x 1000 f32) -> Xb (4096 x 1024 bf16, zero-padded k>=1000)
// ---------------------------------------------------------------------------
__global__ __launch_bounds__(256) void convert_X_kernel(
    const float* __restrict__ X, short* __restrict__ Xb)
{
  int b = blockIdx.x;
  int k = threadIdx.x * 4;
  short4 o;
  if (k < FSZ) {  // 1000 % 4 == 0, rows 16B-aligned (4000B stride)
    float4 v = *(const float4*)(X + (size_t)b * FSZ + k);
    o = make_short4(f2bf(v.x), f2bf(v.y), f2bf(v.z), f2bf(v.w));
  } else {
    o = make_short4(0, 0, 0, 0);
  }
  *(short4*)(Xb + (size_t)b * 1024 + k) = o;
}

// ---------------------------------------------------------------------------
// Mt[n][k] = bf16( M[k][n] ) = (n>k) ? dot(nfk[k,f2f[n],:], nfk[n,f2f[k],:]) : 0
// Mt is 1024 x 1024, zero-padded. grid (4,1024) x 256, coalesced bf16 writes.
// ---------------------------------------------------------------------------
__global__ __launch_bounds__(256) void build_Mt_kernel(
    const float* __restrict__ nfk, const int* __restrict__ f2f,
    short* __restrict__ Mt)
{
  int n = blockIdx.y;
  int k = blockIdx.x * 256 + threadIdx.x;
  float s = 0.f;
  if (n < FSZ && k < FSZ && n > k) {
    int fn = f2f[n], fk = f2f[k];
    const float4* p = (const float4*)(nfk + ((size_t)k * NFIELDS + fn) * KDIM);
    const float4* q = (const float4*)(nfk + ((size_t)n * NFIELDS + fk) * KDIM);
    #pragma unroll
    for (int t = 0; t < KDIM / 4; ++t) {
      float4 a = p[t], b = q[t];
      s += a.x * b.x + a.y * b.y + a.z * b.z + a.w * b.w;
    }
  }
  Mt[(size_t)n * 1024 + k] = f2bf(s);
}

// ---------------------------------------------------------------------------
// out[n][k] = bf16( in[k][n] ), in: K_in x N_in f32; out: N_in x Kpad bf16
// (zero pad K_in..Kpad). 32x32 LDS tile transpose, block 256.
// ---------------------------------------------------------------------------
__global__ __launch_bounds__(256) void transpose_bf16_kernel(
    const float* __restrict__ in, short* __restrict__ out,
    int K_in, int N_in, int Kpad)
{
  __shared__ float t[32][33];
  int n0 = blockIdx.x * 32, k0 = blockIdx.y * 32;
  int tx = threadIdx.x & 31, ty = threadIdx.x >> 5;  // ty 0..7
  #pragma unroll
  for (int i = 0; i < 32; i += 8) {
    int k = k0 + ty + i, n = n0 + tx;
    t[ty + i][tx] = (k < K_in && n < N_in) ? in[(size_t)k * N_in + n] : 0.f;
  }
  __syncthreads();
  #pragma unroll
  for (int i = 0; i < 32; i += 8) {
    int n = n0 + ty + i, k = k0 + tx;
    if (n < N_in && k < Kpad) out[(size_t)n * Kpad + k] = f2bf(t[tx][ty + i]);
  }
}

// ---------------------------------------------------------------------------
// bf16 MFMA GEMM: C = [relu]( A(MxK) * Bt^T + bias ), Bt is N x K (=B^T).
// BM=64, BN=128, BK=64, 256 thr (4 waves 2x2), per-wave 32x64 (2x4 frags).
// LDS XOR-swizzled (byte ^= (row&7)<<4) vs 128B-stride bank conflicts;
// staged via global_load_lds with pre-swizzled global source (rule 21).
// M % 64 == 0, N % 128 == 0, K % 64 == 0 (inputs zero-padded).
// ---------------------------------------------------------------------------
template<int OUT_BF16, int DO_RELU>
__global__ __launch_bounds__(256) void gemm_mfma_kernel(
    const short* __restrict__ A, const short* __restrict__ Bt,
    const float* __restrict__ bias, void* __restrict__ Cout,
    int N, int K)
{
  __shared__ __align__(16) short As[64 * 64];    //  8 KiB
  __shared__ __align__(16) short Bs[128 * 64];   // 16 KiB
  const int tid  = threadIdx.x;
  const int wid  = tid >> 6;
  const int lane = tid & 63;
  const int wr   = wid >> 1, wc = wid & 1;
  const int row0 = blockIdx.y * 64;
  const int col0 = blockIdx.x * 128;

  f32x4 acc[2][4];
  #pragma unroll
  for (int m = 0; m < 2; ++m)
    #pragma unroll
    for (int n = 0; n < 4; ++n) acc[m][n] = (f32x4)(0.f);

  for (int k0 = 0; k0 < K; k0 += 64) {
    __syncthreads();  // previous tile fully consumed
    // ---- stage A: 8 KiB = 8 wave-instrs (2 per wave) ----
    #pragma unroll
    for (int j = 0; j < 2; ++j) {
      int i = 4 * j + wid;
      int o = i * 1024 + lane * 16;
      int r = o >> 7;                              // tile row (128 B rows)
      int cb = (o & 127) ^ ((r & 7) << 4);         // pre-swizzled source col
      const char* src = (const char*)A + (((size_t)(row0 + r) * K + k0) << 1) + cb;
      gload16(src, (char*)As + i * 1024);
    }
    // ---- stage Bt: 16 KiB = 16 wave-instrs (4 per wave) ----
    #pragma unroll
    for (int j = 0; j < 4; ++j) {
      int i = 4 * j + wid;
      int o = i * 1024 + lane * 16;
      int r = o >> 7;
      int cb = (o & 127) ^ ((r & 7) << 4);
      const char* src = (const char*)Bt + (((size_t)(col0 + r) * K + k0) << 1) + cb;
      gload16(src, (char*)Bs + i * 1024);
    }
    asm volatile("s_waitcnt vmcnt(0)" ::: "memory");
    __syncthreads();  // tile visible to all waves
    // ---- compute: 2 k-steps of 32 ----
    #pragma unroll
    for (int kk = 0; kk < 2; ++kk) {
      const int cb = kk * 64 + (lane >> 4) * 16;
      short8v a[2], b[4];
      #pragma unroll
      for (int m = 0; m < 2; ++m) {
        int r = wr * 32 + m * 16 + (lane & 15);
        a[m] = *(const short8v*)((const char*)As + r * 128 + (cb ^ ((r & 7) << 4)));
      }
      #pragma unroll
      for (int n = 0; n < 4; ++n) {
        int r = wc * 64 + n * 16 + (lane & 15);
        b[n] = *(const short8v*)((const char*)Bs + r * 128 + (cb ^ ((r & 7) << 4)));
      }
      #pragma unroll
      for (int m = 0; m < 2; ++m)
        #pragma unroll
        for (int n = 0; n < 4; ++n)
          acc[m][n] = __builtin_amdgcn_mfma_f32_16x16x32_bf16(a[m], b[n], acc[m][n], 0, 0, 0);
    }
  }

  // ---- epilogue: C/D layout col=lane&15, row=(lane>>4)*4+reg ----
  const int cr = (lane >> 4) * 4;
  const int cc = lane & 15;
  #pragma unroll
  for (int m = 0; m < 2; ++m) {
    #pragma unroll
    for (int n = 0; n < 4; ++n) {
      int gc = col0 + wc * 64 + n * 16 + cc;
      float bv = bias ? bias[gc] : 0.f;
      #pragma unroll
      for (int r = 0; r < 4; ++r) {
        int gr = row0 + wr * 32 + m * 16 + cr + r;
        float v = acc[m][n][r] + bv;
        if (DO_RELU) v = fmaxf(v, 0.f);
        if (OUT_BF16) ((short*)Cout)[(size_t)gr * N + gc] = f2bf(v);
        else          ((float*)Cout)[(size_t)gr * N + gc] = v;
      }
    }
  }
}

// ---------------------------------------------------------------------------
// out[b] = X[b]·w1 + b0 + sum_j T[b][j] * X[b][j]   (T stride 1024, fp32)
// ---------------------------------------------------------------------------
__global__ __launch_bounds__(256) void rowdot_kernel(
    const float* __restrict__ X, const float* __restrict__ w1,
    const float* __restrict__ bsc, const float* __restrict__ T,
    float* __restrict__ out)
{
  __shared__ float sm1[4], sm2[4];
  int b = blockIdx.x;
  const float* xr = X + (size_t)b * FSZ;
  const float* tr = T + (size_t)b * 1024;
  float pi = 0.f, pl = 0.f;
  for (int j = threadIdx.x; j < FSZ; j += 256) {
    float x = xr[j];
    pi += tr[j] * x;
    pl += x * w1[j];
  }
  #pragma unroll
  for (int o = 32; o; o >>= 1) {
    pi += __shfl_down(pi, o, 64);
    pl += __shfl_down(pl, o, 64);
  }
  int lane = threadIdx.x & 63, w = threadIdx.x >> 6;
  if (!lane) { sm1[w] = pi; sm2[w] = pl; }
  __syncthreads();
  if (!threadIdx.x)
    out[b] = (sm2[0] + sm2[1] + sm2[2] + sm2[3]) + bsc[0]
           + (sm1[0] + sm1[1] + sm1[2] + sm1[3]);
}

// ---------------------------------------------------------------------------
// out[b] += h2[b]·outW + outB   (h2 fp32, 256 cols)
// ---------------------------------------------------------------------------
__global__ __launch_bounds__(256) void outdot_kernel(
    const float* __restrict__ h2, const float* __restrict__ oW,
    const float* __restrict__ oB, float* __restrict__ out)
{
  __shared__ float sm[4];
  int b = blockIdx.x;
  float p = h2[(size_t)b * 256 + threadIdx.x] * oW[threadIdx.x];
  #pragma unroll
  for (int o = 32; o; o >>= 1) p += __shfl_down(p, o, 64);
  int lane = threadIdx.x & 63, w = threadIdx.x >> 6;
  if (!lane) sm[w] = p;
  __syncthreads();
  if (!threadIdx.x) out[b] += sm[0] + sm[1] + sm[2] + sm[3] + oB[0];
}

// ---------------------------------------------------------------------------
extern "C" void kernel_launch(void* const* d_in, const int* in_sizes, int n_in,
                              void* d_out, int out_size, void* d_ws, size_t ws_size,
                              hipStream_t stream) {
  const float* X   = (const float*)d_in[0];
  const float* w1  = (const float*)d_in[1];
  const float* bsc = (const float*)d_in[2];
  const float* nfk = (const float*)d_in[3];
  const int*   f2f = (const int*)d_in[4];
  const float* W0  = (const float*)d_in[5];
  const float* B0  = (const float*)d_in[6];
  const float* W1  = (const float*)d_in[7];
  const float* B1  = (const float*)d_in[8];
  const float* W2  = (const float*)d_in[9];
  const float* B2  = (const float*)d_in[10];
  const float* oW  = (const float*)d_in[11];
  const float* oB  = (const float*)d_in[12];
  float* out = (float*)d_out;

  char* ws = (char*)d_ws;
  // Overlaid workspace (stream-ordered lifetimes), 30,670,848 B total:
  short* Xb  = (short*)(ws);                    // 8 MiB  [0, 8388608)
  float* T   = (float*)(ws + 8388608);          // 16 MiB [8388608, 25165824)
  short* h0  = (short*)(ws + 8388608);          // 8 MiB  overlays T (after rowdot)
  short* Mt  = (short*)(ws + 25165824);         // 2 MiB
  short* Wt0 = (short*)(ws + 27262976);         // 2 MiB
  short* h1  = (short*)(ws + 25165824);         // 4 MiB  overlays Mt+Wt0 (after GEMM2)
  short* Wt1 = (short*)(ws + 29360128);         // 1 MiB
  short* Wt2 = (short*)(ws + 30408704);         // 256 KiB
  float* h2  = (float*)(ws);                    // 4 MiB  overlays Xb (after GEMM2)

  // 1) conversions / packing
  convert_X_kernel<<<BATCH, 256, 0, stream>>>(X, Xb);
  build_Mt_kernel<<<dim3(4, 1024), 256, 0, stream>>>(nfk, f2f, Mt);
  transpose_bf16_kernel<<<dim3(32, 32), 256, 0, stream>>>(W0, Wt0, 1000, 1024, 1024);
  transpose_bf16_kernel<<<dim3(16, 32), 256, 0, stream>>>(W1, Wt1, 1024,  512, 1024);
  transpose_bf16_kernel<<<dim3( 8, 16), 256, 0, stream>>>(W2, Wt2,  512,  256,  512);

  // 2) T = X @ M   (fp32 out, no bias/relu)  N=1024 K=1024
  gemm_mfma_kernel<0, 0><<<dim3(8, 64), 256, 0, stream>>>(Xb, Mt, nullptr, T, 1024, 1024);
  // 3) out = linear + interaction
  rowdot_kernel<<<BATCH, 256, 0, stream>>>(X, w1, bsc, T, out);
  // 4) h0 = relu(X @ W0 + B0)  (bf16 out)  N=1024 K=1024
  gemm_mfma_kernel<1, 1><<<dim3(8, 64), 256, 0, stream>>>(Xb, Wt0, B0, h0, 1024, 1024);
  // 5) h1 = relu(h0 @ W1 + B1) (bf16 out)  N=512 K=1024
  gemm_mfma_kernel<1, 1><<<dim3(4, 64), 256, 0, stream>>>(h0, Wt1, B1, h1, 512, 1024);
  // 6) h2 = relu(h1 @ W2 + B2) (fp32 out)  N=256 K=512
  gemm_mfma_kernel<0, 1><<<dim3(2, 64), 256, 0, stream>>>(h1, Wt2, B2, h2, 256, 512);
  // 7) out += h2 @ outW + outB
  outdot_kernel<<<BATCH, 256, 0, stream>>>(h2, oW, oB, out);
}

// Round 3
// 87.166 us; speedup vs baseline: 8.1124x; 1.3862x over previous
//
#include <hip/hip_runtime.h>

// ---------------------------------------------------------------------------
// DeepFFM round 3: 5 launches total.
//  1) prep       : X->bf16, Mt build, W0/W1/W2 transpose->bf16 (one kernel)
//  2) gemm12     : [T-partials | h0] = Xb @ [Mt ; Wt0]^T  (N=2048 fused)
//                  T half never materialized: epilogue reduces (acc+w1)*X
//  3) gemm3      : h1 = relu(h0 @ W1 + B1)
//  4) gemm4      : h2 = relu(h1 @ W2 + B2)
//  5) finalize   : out[b] = sum(partial[b]) + b0 + h2[b]·outW + outB
// GEMMs: bf16 MFMA 16x16x32, fp32 acc, double-buffered LDS w/ prefetch,
// XOR-swizzled LDS (linear dest + pre-swizzled global src + swizzled read).
// ---------------------------------------------------------------------------

#define BATCH   4096
#define FSZ     1000
#define NFIELDS 39
#define KDIM    40

typedef __attribute__((ext_vector_type(8))) short short8v;  // 8 x bf16
typedef __attribute__((ext_vector_type(4))) float f32x4;

__device__ __forceinline__ short f2bf(float f) {
  unsigned u = __builtin_bit_cast(unsigned, f);
  u += 0x7fff + ((u >> 16) & 1);   // RNE (finite data)
  return (short)(u >> 16);
}

typedef const __attribute__((address_space(1))) unsigned int* gas_ptr;
typedef __attribute__((address_space(3))) unsigned int* las_ptr;
__device__ __forceinline__ void gload16(const void* g, void* l) {
  __builtin_amdgcn_global_load_lds((gas_ptr)g, (las_ptr)l, 16, 0, 0);
}

// ---------------------------------------------------------------------------
// prep mega-kernel: block ranges
//  [0,4096)      : Xb row conversion (1000 -> 1024 pad)
//  [4096,8192)   : Mt (B12 rows 0..1023)
//  [8192,9216)   : W0^T -> B12 rows 1024..2047
//  [9216,9728)   : W1^T -> Wt1
//  [9728,9856)   : W2^T -> Wt2
// ---------------------------------------------------------------------------
__device__ __forceinline__ void transp32(
    const float* __restrict__ in, short* __restrict__ out, int idx, int nx,
    int K_in, int N_in, int Kpad, float (*t)[33], int tid)
{
  int n0 = (idx % nx) * 32, k0 = (idx / nx) * 32;
  int tx = tid & 31, ty = tid >> 5;
  #pragma unroll
  for (int i = 0; i < 32; i += 8) {
    int k = k0 + ty + i, n = n0 + tx;
    t[ty + i][tx] = (k < K_in && n < N_in) ? in[(size_t)k * N_in + n] : 0.f;
  }
  __syncthreads();
  #pragma unroll
  for (int i = 0; i < 32; i += 8) {
    int n = n0 + ty + i, k = k0 + tx;
    if (n < N_in && k < Kpad) out[(size_t)n * Kpad + k] = f2bf(t[tx][ty + i]);
  }
}

__global__ __launch_bounds__(256) void prep_kernel(
    const float* __restrict__ X, const float* __restrict__ nfk,
    const int* __restrict__ f2f,
    const float* __restrict__ W0, const float* __restrict__ W1,
    const float* __restrict__ W2,
    short* __restrict__ Xb, short* __restrict__ B12,
    short* __restrict__ Wt1, short* __restrict__ Wt2)
{
  __shared__ float tbuf[32][33];
  const int bid = blockIdx.x, tid = threadIdx.x;
  if (bid < 4096) {
    int k = tid * 4;
    short4 o = make_short4(0, 0, 0, 0);
    if (k < FSZ) {
      float4 v = *(const float4*)(X + (size_t)bid * FSZ + k);
      o = make_short4(f2bf(v.x), f2bf(v.y), f2bf(v.z), f2bf(v.w));
    }
    *(short4*)(Xb + (size_t)bid * 1024 + k) = o;
  } else if (bid < 8192) {
    int idx = bid - 4096;
    int n = idx >> 2, k = (idx & 3) * 256 + tid;
    float s = 0.f;
    if (n < FSZ && k < FSZ && n > k) {
      int fn = f2f[n], fk = f2f[k];
      const float4* p = (const float4*)(nfk + ((size_t)k * NFIELDS + fn) * KDIM);
      const float4* q = (const float4*)(nfk + ((size_t)n * NFIELDS + fk) * KDIM);
      #pragma unroll
      for (int t = 0; t < KDIM / 4; ++t) {
        float4 a = p[t], b = q[t];
        s += a.x * b.x + a.y * b.y + a.z * b.z + a.w * b.w;
      }
    }
    B12[(size_t)n * 1024 + k] = f2bf(s);
  } else if (bid < 9216) {
    transp32(W0, B12 + 1024 * 1024, bid - 8192, 32, 1000, 1024, 1024, tbuf, tid);
  } else if (bid < 9728) {
    transp32(W1, Wt1, bid - 9216, 16, 1024, 512, 1024, tbuf, tid);
  } else {
    transp32(W2, Wt2, bid - 9728, 8, 512, 256, 512, tbuf, tid);
  }
}

// ---------------------------------------------------------------------------
// bf16 MFMA GEMM, double-buffered. A: MxK bf16; Bt: NxK bf16 (=B^T).
// 256 thr, 4 waves 2x2, wave tile (BM/2)x(BN/2), frags AM=BM/32, AN=BN/32.
// EPI 0: dual-region (bx<8: interaction partials; bx>=8: h0 bf16 relu)
// EPI 1: bf16 + bias + relu.  EPI 2: f32 + bias + relu.
// ---------------------------------------------------------------------------
template<int BM, int BN, int EPI>
__global__ __launch_bounds__(256) void gemm_mfma(
    const short* __restrict__ A, const short* __restrict__ Bt,
    const float* __restrict__ bias, void* __restrict__ Cout,
    int N, int K,
    const float* __restrict__ X, const float* __restrict__ w1,
    float* __restrict__ partial)
{
  constexpr int AM = BM / 32, AN = BN / 32;
  __shared__ __align__(16) short As[2][BM * 64];
  __shared__ __align__(16) short Bs[2][BN * 64];
  __shared__ float pbuf[2][128];

  const int tid  = threadIdx.x;
  const int wid  = tid >> 6;
  const int lane = tid & 63;
  const int wr   = wid >> 1, wc = wid & 1;
  const int row0 = blockIdx.y * BM;
  const int col0 = blockIdx.x * BN;

  const int lr8   = lane >> 3;        // chunk-local row 0..7
  const int cbase = (lane & 7) * 16;  // byte col within 128B row

  f32x4 acc[AM][AN];
  #pragma unroll
  for (int m = 0; m < AM; ++m)
    #pragma unroll
    for (int n = 0; n < AN; ++n) acc[m][n] = (f32x4)(0.f);

  auto stage = [&](int p, int k0) {
    #pragma unroll
    for (int j = 0; j < BM / 32; ++j) {
      int i = j * 4 + wid;               // 1 KiB chunk = 8 rows
      int r = i * 8 + lr8;
      int cb = cbase ^ ((r & 7) << 4);   // pre-swizzled global source
      gload16((const char*)A + (((size_t)(row0 + r) * K + k0) << 1) + cb,
              (char*)&As[p][0] + i * 1024);
    }
    #pragma unroll
    for (int j = 0; j < BN / 32; ++j) {
      int i = j * 4 + wid;
      int r = i * 8 + lr8;
      int cb = cbase ^ ((r & 7) << 4);
      gload16((const char*)Bt + (((size_t)(col0 + r) * K + k0) << 1) + cb,
              (char*)&Bs[p][0] + i * 1024);
    }
  };

  auto compute = [&](int p) {
    #pragma unroll
    for (int kk = 0; kk < 2; ++kk) {
      const int cb = kk * 64 + (lane >> 4) * 16;
      short8v a[AM], b[AN];
      #pragma unroll
      for (int m = 0; m < AM; ++m) {
        int r = wr * (BM / 2) + m * 16 + (lane & 15);
        a[m] = *(const short8v*)((const char*)&As[p][0] + r * 128 + (cb ^ ((r & 7) << 4)));
      }
      #pragma unroll
      for (int n = 0; n < AN; ++n) {
        int r = wc * (BN / 2) + n * 16 + (lane & 15);
        b[n] = *(const short8v*)((const char*)&Bs[p][0] + r * 128 + (cb ^ ((r & 7) << 4)));
      }
      #pragma unroll
      for (int m = 0; m < AM; ++m)
        #pragma unroll
        for (int n = 0; n < AN; ++n)
          acc[m][n] = __builtin_amdgcn_mfma_f32_16x16x32_bf16(a[m], b[n], acc[m][n], 0, 0, 0);
    }
  };

  const int nt = K >> 6;
  stage(0, 0);
  __syncthreads();
  for (int t = 0; t < nt; ++t) {
    if (t + 1 < nt) stage((t + 1) & 1, (t + 1) << 6);  // prefetch next tile
    compute(t & 1);                                     // overlaps w/ loads
    __syncthreads();                                    // drain + swap
  }

  const int cr = (lane >> 4) * 4;
  const int cc = lane & 15;

  if (EPI == 0) {
    if (blockIdx.x < 8) {
      // interaction + linear partials: sum_c (acc + w1[c]) * X[r][c]
      float rsum[AM * 4];
      #pragma unroll
      for (int i = 0; i < AM * 4; ++i) rsum[i] = 0.f;
      #pragma unroll
      for (int m = 0; m < AM; ++m) {
        #pragma unroll
        for (int n = 0; n < AN; ++n) {
          int gc = col0 + wc * (BN / 2) + n * 16 + cc;
          bool ok = gc < FSZ;
          float w1v = ok ? w1[gc] : 0.f;
          #pragma unroll
          for (int r = 0; r < 4; ++r) {
            int gr = row0 + wr * (BM / 2) + m * 16 + cr + r;
            float xv = ok ? X[(size_t)gr * FSZ + gc] : 0.f;
            rsum[m * 4 + r] = fmaf(acc[m][n][r] + w1v, xv, rsum[m * 4 + r]);
          }
        }
      }
      #pragma unroll
      for (int mask = 1; mask < 16; mask <<= 1)
        #pragma unroll
        for (int i = 0; i < AM * 4; ++i)
          rsum[i] += __shfl_xor(rsum[i], mask, 64);
      if (cc == 0) {
        #pragma unroll
        for (int m = 0; m < AM; ++m)
          #pragma unroll
          for (int r = 0; r < 4; ++r)
            pbuf[wc][wr * (BM / 2) + m * 16 + cr + r] = rsum[m * 4 + r];
      }
      __syncthreads();
      if (tid < BM)
        partial[(size_t)(row0 + tid) * 8 + blockIdx.x] = pbuf[0][tid] + pbuf[1][tid];
    } else {
      // h0 = relu(X@W0 + B0), bf16, stride 1024
      #pragma unroll
      for (int m = 0; m < AM; ++m) {
        #pragma unroll
        for (int n = 0; n < AN; ++n) {
          int gc = col0 - 1024 + wc * (BN / 2) + n * 16 + cc;
          float bv = bias[gc];
          #pragma unroll
          for (int r = 0; r < 4; ++r) {
            int gr = row0 + wr * (BM / 2) + m * 16 + cr + r;
            float v = fmaxf(acc[m][n][r] + bv, 0.f);
            ((short*)Cout)[(size_t)gr * 1024 + gc] = f2bf(v);
          }
        }
      }
    }
  } else {
    #pragma unroll
    for (int m = 0; m < AM; ++m) {
      #pragma unroll
      for (int n = 0; n < AN; ++n) {
        int gc = col0 + wc * (BN / 2) + n * 16 + cc;
        float bv = bias[gc];
        #pragma unroll
        for (int r = 0; r < 4; ++r) {
          int gr = row0 + wr * (BM / 2) + m * 16 + cr + r;
          float v = fmaxf(acc[m][n][r] + bv, 0.f);
          if (EPI == 1) ((short*)Cout)[(size_t)gr * N + gc] = f2bf(v);
          else          ((float*)Cout)[(size_t)gr * N + gc] = v;
        }
      }
    }
  }
}

// ---------------------------------------------------------------------------
// finalize: out[b] = sum_8(partial[b]) + b0 + h2[b]·outW + outB
// ---------------------------------------------------------------------------
__global__ __launch_bounds__(256) void finalize_kernel(
    const float* __restrict__ h2, const float* __restrict__ oW,
    const float* __restrict__ oB, const float* __restrict__ bsc,
    const float* __restrict__ partial, float* __restrict__ out)
{
  __shared__ float sm[4];
  int b = blockIdx.x, t = threadIdx.x;
  float p = h2[(size_t)b * 256 + t] * oW[t];
  if (t < 8) p += partial[(size_t)b * 8 + t];
  #pragma unroll
  for (int o = 32; o; o >>= 1) p += __shfl_down(p, o, 64);
  int lane = t & 63, w = t >> 6;
  if (!lane) sm[w] = p;
  __syncthreads();
  if (!t) out[b] = sm[0] + sm[1] + sm[2] + sm[3] + bsc[0] + oB[0];
}

// ---------------------------------------------------------------------------
extern "C" void kernel_launch(void* const* d_in, const int* in_sizes, int n_in,
                              void* d_out, int out_size, void* d_ws, size_t ws_size,
                              hipStream_t stream) {
  const float* X   = (const float*)d_in[0];
  const float* w1  = (const float*)d_in[1];
  const float* bsc = (const float*)d_in[2];
  const float* nfk = (const float*)d_in[3];
  const int*   f2f = (const int*)d_in[4];
  const float* W0  = (const float*)d_in[5];
  const float* B0  = (const float*)d_in[6];
  const float* W1  = (const float*)d_in[7];
  const float* B1  = (const float*)d_in[8];
  const float* W2  = (const float*)d_in[9];
  const float* B2  = (const float*)d_in[10];
  const float* oW  = (const float*)d_in[11];
  const float* oB  = (const float*)d_in[12];
  float* out = (float*)d_out;

  char* ws = (char*)d_ws;
  short* Xb   = (short*)(ws);                 // 8,388,608
  short* B12  = (short*)(ws + 8388608);       // 4,194,304 (Mt rows 0..1023, Wt0 rows 1024..2047)
  short* Wt1  = (short*)(ws + 12582912);      // 1,048,576
  short* Wt2  = (short*)(ws + 13631488);      //   262,144
  float* part = (float*)(ws + 13893632);      //   131,072
  short* h0   = (short*)(ws + 14680064);      // 8,388,608
  short* h1   = (short*)(ws + 23068672);      // 4,194,304
  float* h2   = (float*)(ws + 27262976);      // 4,194,304  -> total 31,457,280 B

  // 1) prep (all conversions/packing)
  prep_kernel<<<9856, 256, 0, stream>>>(X, nfk, f2f, W0, W1, W2,
                                        Xb, B12, Wt1, Wt2);
  // 2) fused [T-partials | h0] GEMM: N=2048, K=1024
  gemm_mfma<128, 128, 0><<<dim3(16, 32), 256, 0, stream>>>(
      Xb, B12, B0, h0, 2048, 1024, X, w1, part);
  // 3) h1 = relu(h0 @ W1 + B1): N=512, K=1024
  gemm_mfma<64, 128, 1><<<dim3(4, 64), 256, 0, stream>>>(
      h0, Wt1, B1, h1, 512, 1024, nullptr, nullptr, nullptr);
  // 4) h2 = relu(h1 @ W2 + B2): N=256, K=512
  gemm_mfma<64, 64, 2><<<dim3(4, 64), 256, 0, stream>>>(
      h1, Wt2, B2, h2, 256, 512, nullptr, nullptr, nullptr);
  // 5) out
  finalize_kernel<<<BATCH, 256, 0, stream>>>(h2, oW, oB, bsc, part, out);
}

// Round 4
// 83.736 us; speedup vs baseline: 8.4447x; 1.0410x over previous
//
#include <hip/hip_runtime.h>

// ---------------------------------------------------------------------------
// DeepFFM round 4: 5 launches.
//  1) prep     : X->bf16(pad), Mt build, W0/W1/W2 transpose->bf16 (one kernel)
//  2) gemm12   : [T-partials | h0] = Xb @ [Mt ; Wt0]^T  (N=2048 fused)
//                - interaction half: triangular K-skip (Mt is triu -> tiles
//                  with k0 >= col0+128 are exactly zero, skipped)
//                - T never materialized: epilogue reduces (acc+w1)*X -> part[8]
//  3) gemm3    : h1 = relu(h0 @ W1 + B1)
//  4) gemm4    : h2 never materialized: epilogue reduces relu(acc+B2)*outW
//                -> part2[4]
//  5) finalize : out[b] = sum(part) + sum(part2) + b0 + outB
// GEMMs: bf16 MFMA 16x16x32, fp32 acc, double-buffered LDS, 2-phase prefetch,
// XOR-swizzled LDS (linear dest + pre-swizzled global src + swizzled read).
// ---------------------------------------------------------------------------

#define BATCH   4096
#define FSZ     1000
#define NFIELDS 39
#define KDIM    40

typedef __attribute__((ext_vector_type(8))) short short8v;  // 8 x bf16
typedef __attribute__((ext_vector_type(4))) float f32x4;

__device__ __forceinline__ short f2bf(float f) {
  unsigned u = __builtin_bit_cast(unsigned, f);
  u += 0x7fff + ((u >> 16) & 1);   // RNE (finite data)
  return (short)(u >> 16);
}

typedef const __attribute__((address_space(1))) unsigned int* gas_ptr;
typedef __attribute__((address_space(3))) unsigned int* las_ptr;
__device__ __forceinline__ void gload16(const void* g, void* l) {
  __builtin_amdgcn_global_load_lds((gas_ptr)g, (las_ptr)l, 16, 0, 0);
}

// ---------------------------------------------------------------------------
// prep mega-kernel: block ranges
//  [0,4096)      : Xb row conversion (1000 -> 1024 pad)
//  [4096,8192)   : Mt (B12 rows 0..1023)
//  [8192,9216)   : W0^T -> B12 rows 1024..2047
//  [9216,9728)   : W1^T -> Wt1
//  [9728,9856)   : W2^T -> Wt2
// ---------------------------------------------------------------------------
__device__ __forceinline__ void transp32(
    const float* __restrict__ in, short* __restrict__ out, int idx, int nx,
    int K_in, int N_in, int Kpad, float (*t)[33], int tid)
{
  int n0 = (idx % nx) * 32, k0 = (idx / nx) * 32;
  int tx = tid & 31, ty = tid >> 5;
  #pragma unroll
  for (int i = 0; i < 32; i += 8) {
    int k = k0 + ty + i, n = n0 + tx;
    t[ty + i][tx] = (k < K_in && n < N_in) ? in[(size_t)k * N_in + n] : 0.f;
  }
  __syncthreads();
  #pragma unroll
  for (int i = 0; i < 32; i += 8) {
    int n = n0 + ty + i, k = k0 + tx;
    if (n < N_in && k < Kpad) out[(size_t)n * Kpad + k] = f2bf(t[tx][ty + i]);
  }
}

__global__ __launch_bounds__(256) void prep_kernel(
    const float* __restrict__ X, const float* __restrict__ nfk,
    const int* __restrict__ f2f,
    const float* __restrict__ W0, const float* __restrict__ W1,
    const float* __restrict__ W2,
    short* __restrict__ Xb, short* __restrict__ B12,
    short* __restrict__ Wt1, short* __restrict__ Wt2)
{
  __shared__ float tbuf[32][33];
  const int bid = blockIdx.x, tid = threadIdx.x;
  if (bid < 4096) {
    int k = tid * 4;
    short4 o = make_short4(0, 0, 0, 0);
    if (k < FSZ) {
      float4 v = *(const float4*)(X + (size_t)bid * FSZ + k);
      o = make_short4(f2bf(v.x), f2bf(v.y), f2bf(v.z), f2bf(v.w));
    }
    *(short4*)(Xb + (size_t)bid * 1024 + k) = o;
  } else if (bid < 8192) {
    int idx = bid - 4096;
    int n = idx >> 2, k = (idx & 3) * 256 + tid;
    float s = 0.f;
    if (n < FSZ && k < FSZ && n > k) {
      int fn = f2f[n], fk = f2f[k];
      const float4* p = (const float4*)(nfk + ((size_t)k * NFIELDS + fn) * KDIM);
      const float4* q = (const float4*)(nfk + ((size_t)n * NFIELDS + fk) * KDIM);
      #pragma unroll
      for (int t = 0; t < KDIM / 4; ++t) {
        float4 a = p[t], b = q[t];
        s += a.x * b.x + a.y * b.y + a.z * b.z + a.w * b.w;
      }
    }
    B12[(size_t)n * 1024 + k] = f2bf(s);
  } else if (bid < 9216) {
    transp32(W0, B12 + 1024 * 1024, bid - 8192, 32, 1000, 1024, 1024, tbuf, tid);
  } else if (bid < 9728) {
    transp32(W1, Wt1, bid - 9216, 16, 1024, 512, 1024, tbuf, tid);
  } else {
    transp32(W2, Wt2, bid - 9728, 8, 512, 256, 512, tbuf, tid);
  }
}

// ---------------------------------------------------------------------------
// bf16 MFMA GEMM, double-buffered. A: MxK bf16; Bt: NxK bf16 (=B^T).
// 256 thr, 4 waves 2x2, wave tile (BM/2)x(BN/2), frags AM=BM/32, AN=BN/32.
// EPI 0: dual-region (bx<8: interaction+linear partials w/ triangular K-skip;
//        bx>=8: h0 bf16 relu, stride 1024)
// EPI 1: bf16 + bias + relu
// EPI 3: fused out-dot: part2[row][bx] = sum_c relu(acc+bias[c])*oW[c]
// ---------------------------------------------------------------------------
template<int BM, int BN, int EPI>
__global__ __launch_bounds__(256) void gemm_mfma(
    const short* __restrict__ A, const short* __restrict__ Bt,
    const float* __restrict__ bias, void* __restrict__ Cout,
    int N, int K,
    const float* __restrict__ X, const float* __restrict__ w1,
    float* __restrict__ partial)
{
  constexpr int AM = BM / 32, AN = BN / 32;
  __shared__ __align__(16) short As[2][BM * 64];
  __shared__ __align__(16) short Bs[2][BN * 64];
  __shared__ float pbuf[2][BM];

  const int tid  = threadIdx.x;
  const int wid  = tid >> 6;
  const int lane = tid & 63;
  const int wr   = wid >> 1, wc = wid & 1;
  const int row0 = blockIdx.y * BM;
  const int col0 = blockIdx.x * BN;

  const int lr8   = lane >> 3;        // chunk-local row 0..7
  const int cbase = (lane & 7) * 16;  // byte col within 128B row

  f32x4 acc[AM][AN];
  #pragma unroll
  for (int m = 0; m < AM; ++m)
    #pragma unroll
    for (int n = 0; n < AN; ++n) acc[m][n] = (f32x4)(0.f);

  auto stage = [&](int p, int k0) {
    #pragma unroll
    for (int j = 0; j < BM / 32; ++j) {
      int i = j * 4 + wid;               // 1 KiB chunk = 8 rows
      int r = i * 8 + lr8;
      int cb = cbase ^ ((r & 7) << 4);   // pre-swizzled global source
      gload16((const char*)A + (((size_t)(row0 + r) * K + k0) << 1) + cb,
              (char*)&As[p][0] + i * 1024);
    }
    #pragma unroll
    for (int j = 0; j < BN / 32; ++j) {
      int i = j * 4 + wid;
      int r = i * 8 + lr8;
      int cb = cbase ^ ((r & 7) << 4);
      gload16((const char*)Bt + (((size_t)(col0 + r) * K + k0) << 1) + cb,
              (char*)&Bs[p][0] + i * 1024);
    }
  };

  auto compute = [&](int p) {
    #pragma unroll
    for (int kk = 0; kk < 2; ++kk) {
      const int cb = kk * 64 + (lane >> 4) * 16;
      short8v a[AM], b[AN];
      #pragma unroll
      for (int m = 0; m < AM; ++m) {
        int r = wr * (BM / 2) + m * 16 + (lane & 15);
        a[m] = *(const short8v*)((const char*)&As[p][0] + r * 128 + (cb ^ ((r & 7) << 4)));
      }
      #pragma unroll
      for (int n = 0; n < AN; ++n) {
        int r = wc * (BN / 2) + n * 16 + (lane & 15);
        b[n] = *(const short8v*)((const char*)&Bs[p][0] + r * 128 + (cb ^ ((r & 7) << 4)));
      }
      #pragma unroll
      for (int m = 0; m < AM; ++m)
        #pragma unroll
        for (int n = 0; n < AN; ++n)
          acc[m][n] = __builtin_amdgcn_mfma_f32_16x16x32_bf16(a[m], b[n], acc[m][n], 0, 0, 0);
    }
  };

  // Triangular K-skip: interaction cols [col0, col0+BN) only need k < col0+BN
  // (Mt is strictly upper-triangular; later K-tiles are exactly zero).
  int nt = K >> 6;
  if (EPI == 0 && blockIdx.x < 8) {
    int need = ((int)blockIdx.x * 2) + 2;   // ceil((col0+BN-1)/64)
    nt = nt < need ? nt : need;
  }

  stage(0, 0);
  __syncthreads();
  for (int t = 0; t < nt; ++t) {
    if (t + 1 < nt) stage((t + 1) & 1, (t + 1) << 6);  // prefetch next tile
    compute(t & 1);                                     // overlaps w/ loads
    __syncthreads();                                    // drain + swap
  }

  const int cr = (lane >> 4) * 4;
  const int cc = lane & 15;

  if (EPI == 0) {
    if (blockIdx.x < 8) {
      // interaction + linear partials: sum_c (acc + w1[c]) * X[r][c]
      float rsum[AM * 4];
      #pragma unroll
      for (int i = 0; i < AM * 4; ++i) rsum[i] = 0.f;
      #pragma unroll
      for (int m = 0; m < AM; ++m) {
        #pragma unroll
        for (int n = 0; n < AN; ++n) {
          int gc = col0 + wc * (BN / 2) + n * 16 + cc;
          bool ok = gc < FSZ;
          float w1v = ok ? w1[gc] : 0.f;
          #pragma unroll
          for (int r = 0; r < 4; ++r) {
            int gr = row0 + wr * (BM / 2) + m * 16 + cr + r;
            float xv = ok ? X[(size_t)gr * FSZ + gc] : 0.f;
            rsum[m * 4 + r] = fmaf(acc[m][n][r] + w1v, xv, rsum[m * 4 + r]);
          }
        }
      }
      #pragma unroll
      for (int mask = 1; mask < 16; mask <<= 1)
        #pragma unroll
        for (int i = 0; i < AM * 4; ++i)
          rsum[i] += __shfl_xor(rsum[i], mask, 64);
      if (cc == 0) {
        #pragma unroll
        for (int m = 0; m < AM; ++m)
          #pragma unroll
          for (int r = 0; r < 4; ++r)
            pbuf[wc][wr * (BM / 2) + m * 16 + cr + r] = rsum[m * 4 + r];
      }
      __syncthreads();
      if (tid < BM)
        partial[(size_t)(row0 + tid) * 8 + blockIdx.x] = pbuf[0][tid] + pbuf[1][tid];
    } else {
      // h0 = relu(X@W0 + B0), bf16, stride 1024
      #pragma unroll
      for (int m = 0; m < AM; ++m) {
        #pragma unroll
        for (int n = 0; n < AN; ++n) {
          int gc = col0 - 1024 + wc * (BN / 2) + n * 16 + cc;
          float bv = bias[gc];
          #pragma unroll
          for (int r = 0; r < 4; ++r) {
            int gr = row0 + wr * (BM / 2) + m * 16 + cr + r;
            float v = fmaxf(acc[m][n][r] + bv, 0.f);
            ((short*)Cout)[(size_t)gr * 1024 + gc] = f2bf(v);
          }
        }
      }
    }
  } else if (EPI == 1) {
    #pragma unroll
    for (int m = 0; m < AM; ++m) {
      #pragma unroll
      for (int n = 0; n < AN; ++n) {
        int gc = col0 + wc * (BN / 2) + n * 16 + cc;
        float bv = bias[gc];
        #pragma unroll
        for (int r = 0; r < 4; ++r) {
          int gr = row0 + wr * (BM / 2) + m * 16 + cr + r;
          float v = fmaxf(acc[m][n][r] + bv, 0.f);
          ((short*)Cout)[(size_t)gr * N + gc] = f2bf(v);
        }
      }
    }
  } else {
    // EPI 3: part2[row][bx] = sum_c relu(acc + bias[c]) * oW[c]   (oW in w1)
    float rsum[AM * 4];
    #pragma unroll
    for (int i = 0; i < AM * 4; ++i) rsum[i] = 0.f;
    #pragma unroll
    for (int m = 0; m < AM; ++m) {
      #pragma unroll
      for (int n = 0; n < AN; ++n) {
        int gc = col0 + wc * (BN / 2) + n * 16 + cc;
        float bv = bias[gc];
        float ow = w1[gc];
        #pragma unroll
        for (int r = 0; r < 4; ++r) {
          float v = fmaxf(acc[m][n][r] + bv, 0.f);
          rsum[m * 4 + r] = fmaf(v, ow, rsum[m * 4 + r]);
        }
      }
    }
    #pragma unroll
    for (int mask = 1; mask < 16; mask <<= 1)
      #pragma unroll
      for (int i = 0; i < AM * 4; ++i)
        rsum[i] += __shfl_xor(rsum[i], mask, 64);
    if (cc == 0) {
      #pragma unroll
      for (int m = 0; m < AM; ++m)
        #pragma unroll
        for (int r = 0; r < 4; ++r)
          pbuf[wc][wr * (BM / 2) + m * 16 + cr + r] = rsum[m * 4 + r];
    }
    __syncthreads();
    if (tid < BM)
      partial[(size_t)(row0 + tid) * 4 + blockIdx.x] = pbuf[0][tid] + pbuf[1][tid];
  }
}

// ---------------------------------------------------------------------------
// finalize: out[b] = sum_8(part[b]) + sum_4(part2[b]) + b0 + outB
// ---------------------------------------------------------------------------
__global__ __launch_bounds__(256) void finalize_kernel(
    const float* __restrict__ part, const float* __restrict__ part2,
    const float* __restrict__ bsc, const float* __restrict__ oB,
    float* __restrict__ out)
{
  int b = blockIdx.x * 256 + threadIdx.x;
  const float4* p = (const float4*)(part + (size_t)b * 8);
  float4 a = p[0], c = p[1];
  float4 d = *(const float4*)(part2 + (size_t)b * 4);
  out[b] = a.x + a.y + a.z + a.w + c.x + c.y + c.z + c.w
         + d.x + d.y + d.z + d.w + bsc[0] + oB[0];
}

// ---------------------------------------------------------------------------
extern "C" void kernel_launch(void* const* d_in, const int* in_sizes, int n_in,
                              void* d_out, int out_size, void* d_ws, size_t ws_size,
                              hipStream_t stream) {
  const float* X   = (const float*)d_in[0];
  const float* w1  = (const float*)d_in[1];
  const float* bsc = (const float*)d_in[2];
  const float* nfk = (const float*)d_in[3];
  const int*   f2f = (const int*)d_in[4];
  const float* W0  = (const float*)d_in[5];
  const float* B0  = (const float*)d_in[6];
  const float* W1  = (const float*)d_in[7];
  const float* B1  = (const float*)d_in[8];
  const float* W2  = (const float*)d_in[9];
  const float* B2  = (const float*)d_in[10];
  const float* oW  = (const float*)d_in[11];
  const float* oB  = (const float*)d_in[12];
  float* out = (float*)d_out;

  char* ws = (char*)d_ws;
  short* Xb    = (short*)(ws);                 // 8,388,608
  short* B12   = (short*)(ws + 8388608);       // 4,194,304 (Mt 0..1023, Wt0 1024..2047)
  short* Wt1   = (short*)(ws + 12582912);      // 1,048,576
  short* Wt2   = (short*)(ws + 13631488);      //   262,144
  float* part  = (float*)(ws + 13893632);      //   131,072 (4096 x 8)
  float* part2 = (float*)(ws + 14024704);      //    65,536 (4096 x 4)
  short* h0    = (short*)(ws + 14680064);      // 8,388,608
  short* h1    = (short*)(ws + 23068672);      // 4,194,304  -> total 27,262,976 B

  // 1) prep (all conversions/packing)
  prep_kernel<<<9856, 256, 0, stream>>>(X, nfk, f2f, W0, W1, W2,
                                        Xb, B12, Wt1, Wt2);
  // 2) fused [T-partials | h0] GEMM: N=2048, K=1024 (triangular skip bx<8)
  gemm_mfma<128, 128, 0><<<dim3(16, 32), 256, 0, stream>>>(
      Xb, B12, B0, h0, 2048, 1024, X, w1, part);
  // 3) h1 = relu(h0 @ W1 + B1): N=512, K=1024
  gemm_mfma<64, 128, 1><<<dim3(4, 64), 256, 0, stream>>>(
      h0, Wt1, B1, h1, 512, 1024, nullptr, nullptr, nullptr);
  // 4) fused h2/out-dot: N=256, K=512 -> part2
  gemm_mfma<64, 64, 3><<<dim3(4, 64), 256, 0, stream>>>(
      h1, Wt2, B2, nullptr, 256, 512, nullptr, oW, part2);
  // 5) out
  finalize_kernel<<<16, 256, 0, stream>>>(part, part2, bsc, oB, out);
}

// Round 5
// 79.861 us; speedup vs baseline: 8.8545x; 1.0485x over previous
//
#include <hip/hip_runtime.h>

// ---------------------------------------------------------------------------
// DeepFFM round 5: 4 launches.
//  1) prep     : X->bf16(pad), Mt build (LDS-cached nfk row), W0/W1/W2 -> bf16^T
//  2) gemm12   : [T-partials | h0] = Xb @ [Mt ; Wt0]^T  (N=2048 fused)
//                triangular K-skip on interaction half; partials from Xb(bf16)
//  3) gemm3    : h1 = relu(h0 @ W1 + B1)   (64x64 tiles, 512 blocks)
//  4) gemm4    : BN=256 (full N) + fused out-dot + finalize -> writes out[]
// GEMMs: bf16 MFMA 16x16x32, fp32 acc, SINGLE-buffer m97 2-barrier loop
// (32 KB LDS @128^2 -> 3-4 blocks/CU for inter-block latency hiding),
// XOR-swizzled LDS (linear dest + pre-swizzled global src + swizzled read).
// ---------------------------------------------------------------------------

#define BATCH   4096
#define FSZ     1000
#define NFIELDS 39
#define KDIM    40

typedef __attribute__((ext_vector_type(8))) short short8v;  // 8 x bf16
typedef __attribute__((ext_vector_type(4))) float f32x4;

__device__ __forceinline__ short f2bf(float f) {
  unsigned u = __builtin_bit_cast(unsigned, f);
  u += 0x7fff + ((u >> 16) & 1);   // RNE (finite data)
  return (short)(u >> 16);
}
__device__ __forceinline__ float bf2f(unsigned short h) {
  unsigned u = (unsigned)h << 16;
  return __builtin_bit_cast(float, u);
}

typedef const __attribute__((address_space(1))) unsigned int* gas_ptr;
typedef __attribute__((address_space(3))) unsigned int* las_ptr;
__device__ __forceinline__ void gload16(const void* g, void* l) {
  __builtin_amdgcn_global_load_lds((gas_ptr)g, (las_ptr)l, 16, 0, 0);
}

// ---------------------------------------------------------------------------
// prep mega-kernel: block ranges
//  [0,4096)     : Xb row conversion (1000 -> 1024 pad)
//  [4096,5120)  : Mt row n (B12 rows 0..1023), nfk[n,:,:] cached in LDS
//  [5120,6144)  : W0^T -> B12 rows 1024..2047
//  [6144,6656)  : W1^T -> Wt1
//  [6656,6784)  : W2^T -> Wt2
// ---------------------------------------------------------------------------
__device__ __forceinline__ void transp32(
    const float* __restrict__ in, short* __restrict__ out, int idx, int nx,
    int K_in, int N_in, int Kpad, float (*t)[33], int tid)
{
  int n0 = (idx % nx) * 32, k0 = (idx / nx) * 32;
  int tx = tid & 31, ty = tid >> 5;
  #pragma unroll
  for (int i = 0; i < 32; i += 8) {
    int k = k0 + ty + i, n = n0 + tx;
    t[ty + i][tx] = (k < K_in && n < N_in) ? in[(size_t)k * N_in + n] : 0.f;
  }
  __syncthreads();
  #pragma unroll
  for (int i = 0; i < 32; i += 8) {
    int n = n0 + ty + i, k = k0 + tx;
    if (n < N_in && k < Kpad) out[(size_t)n * Kpad + k] = f2bf(t[tx][ty + i]);
  }
}

__global__ __launch_bounds__(256) void prep_kernel(
    const float* __restrict__ X, const float* __restrict__ nfk,
    const int* __restrict__ f2f,
    const float* __restrict__ W0, const float* __restrict__ W1,
    const float* __restrict__ W2,
    short* __restrict__ Xb, short* __restrict__ B12,
    short* __restrict__ Wt1, short* __restrict__ Wt2)
{
  __shared__ float tbuf[32][33];   // transp32 (aliases C via union-by-extent)
  __shared__ float C[NFIELDS * 44]; // Mt: nfk[n,:,:], stride 44 (16B-aligned)
  const int bid = blockIdx.x, tid = threadIdx.x;
  if (bid < 4096) {
    int k = tid * 4;
    short4 o = make_short4(0, 0, 0, 0);
    if (k < FSZ) {
      float4 v = *(const float4*)(X + (size_t)bid * FSZ + k);
      o = make_short4(f2bf(v.x), f2bf(v.y), f2bf(v.z), f2bf(v.w));
    }
    *(short4*)(Xb + (size_t)bid * 1024 + k) = o;
  } else if (bid < 5120) {
    int n = bid - 4096;
    if (n < FSZ) {
      for (int t = tid; t < NFIELDS * KDIM; t += 256)
        C[(t / KDIM) * 44 + (t % KDIM)] = nfk[(size_t)n * (NFIELDS * KDIM) + t];
    }
    __syncthreads();
    int fn = (n < FSZ) ? f2f[n] : 0;
    #pragma unroll
    for (int kk = 0; kk < 4; ++kk) {
      int k = kk * 256 + tid;
      float s = 0.f;
      if (n < FSZ && k < n) {          // k < n <= FSZ-1 -> k in range
        int fk = f2f[k];
        const float4* p = (const float4*)(nfk + ((size_t)k * NFIELDS + fn) * KDIM);
        const float4* q = (const float4*)&C[fk * 44];
        #pragma unroll
        for (int t = 0; t < KDIM / 4; ++t) {
          float4 a = p[t], b = q[t];
          s += a.x * b.x + a.y * b.y + a.z * b.z + a.w * b.w;
        }
      }
      B12[(size_t)n * 1024 + k] = f2bf(s);
    }
  } else if (bid < 6144) {
    transp32(W0, B12 + 1024 * 1024, bid - 5120, 32, 1000, 1024, 1024, tbuf, tid);
  } else if (bid < 6656) {
    transp32(W1, Wt1, bid - 6144, 16, 1024, 512, 1024, tbuf, tid);
  } else {
    transp32(W2, Wt2, bid - 6656, 8, 512, 256, 512, tbuf, tid);
  }
}

// ---------------------------------------------------------------------------
// bf16 MFMA GEMM, single-buffer 2-barrier (m97). A: MxK bf16; Bt: NxK (=B^T).
// 256 thr, 4 waves 2x2, wave tile (BM/2)x(BN/2), frags AM=BM/32, AN=BN/32.
// EPI 0: dual (bx<8: interaction+linear partials, tri-K-skip, Xb-based;
//        bx>=8: h0 bf16 relu, stride 1024)
// EPI 1: bf16 + bias + relu
// EPI 3: fused out-dot + finalize: out[r] = sum_c relu(acc+bias[c])*oW[c]
//        + sum_8 part[r] + b0 + outB      (requires BN == N)
// ---------------------------------------------------------------------------
template<int BM, int BN, int EPI>
__global__ __launch_bounds__(256) void gemm_mfma(
    const short* __restrict__ A, const short* __restrict__ Bt,
    const float* __restrict__ bias, void* __restrict__ Cout,
    int N, int K,
    const short* __restrict__ Xb, const float* __restrict__ w1,
    float* __restrict__ partial,
    const float* __restrict__ c1, const float* __restrict__ c2)
{
  constexpr int AM = BM / 32, AN = BN / 32;
  __shared__ __align__(16) short As[BM * 64];
  __shared__ __align__(16) short Bs[BN * 64];
  __shared__ float pbuf[2][BM];

  const int tid  = threadIdx.x;
  const int wid  = tid >> 6;
  const int lane = tid & 63;
  const int wr   = wid >> 1, wc = wid & 1;
  const int row0 = blockIdx.y * BM;
  const int col0 = blockIdx.x * BN;

  const int lr8   = lane >> 3;        // chunk-local row 0..7
  const int cbase = (lane & 7) * 16;  // byte col within 128B row

  f32x4 acc[AM][AN];
  #pragma unroll
  for (int m = 0; m < AM; ++m)
    #pragma unroll
    for (int n = 0; n < AN; ++n) acc[m][n] = (f32x4)(0.f);

  auto stage = [&](int k0) {
    #pragma unroll
    for (int j = 0; j < BM / 32; ++j) {
      int i = j * 4 + wid;               // 1 KiB chunk = 8 rows
      int r = i * 8 + lr8;
      int cb = cbase ^ ((r & 7) << 4);   // pre-swizzled global source
      gload16((const char*)A + (((size_t)(row0 + r) * K + k0) << 1) + cb,
              (char*)As + i * 1024);
    }
    #pragma unroll
    for (int j = 0; j < BN / 32; ++j) {
      int i = j * 4 + wid;
      int r = i * 8 + lr8;
      int cb = cbase ^ ((r & 7) << 4);
      gload16((const char*)Bt + (((size_t)(col0 + r) * K + k0) << 1) + cb,
              (char*)Bs + i * 1024);
    }
  };

  auto compute = [&]() {
    #pragma unroll
    for (int kk = 0; kk < 2; ++kk) {
      const int cb = kk * 64 + (lane >> 4) * 16;
      short8v a[AM], b[AN];
      #pragma unroll
      for (int m = 0; m < AM; ++m) {
        int r = wr * (BM / 2) + m * 16 + (lane & 15);
        a[m] = *(const short8v*)((const char*)As + r * 128 + (cb ^ ((r & 7) << 4)));
      }
      #pragma unroll
      for (int n = 0; n < AN; ++n) {
        int r = wc * (BN / 2) + n * 16 + (lane & 15);
        b[n] = *(const short8v*)((const char*)Bs + r * 128 + (cb ^ ((r & 7) << 4)));
      }
      #pragma unroll
      for (int m = 0; m < AM; ++m)
        #pragma unroll
        for (int n = 0; n < AN; ++n)
          acc[m][n] = __builtin_amdgcn_mfma_f32_16x16x32_bf16(a[m], b[n], acc[m][n], 0, 0, 0);
    }
  };

  // Triangular K-skip: interaction cols [col0, col0+BN) only need k < col0+BN
  int nt = K >> 6;
  if (EPI == 0 && blockIdx.x < 8) {
    int need = ((int)blockIdx.x * 2) + 2;
    nt = nt < need ? nt : need;
  }

  for (int t = 0; t < nt; ++t) {
    __syncthreads();                                   // prev tile consumed
    stage(t << 6);
    asm volatile("s_waitcnt vmcnt(0)" ::: "memory");
    __syncthreads();                                   // tile visible
    compute();
  }

  const int cr = (lane >> 4) * 4;
  const int cc = lane & 15;

  if (EPI == 0) {
    if (blockIdx.x < 8) {
      // interaction + linear partials: sum_c (acc + w1[c]) * Xb[r][c]
      float rsum[AM * 4];
      #pragma unroll
      for (int i = 0; i < AM * 4; ++i) rsum[i] = 0.f;
      #pragma unroll
      for (int m = 0; m < AM; ++m) {
        #pragma unroll
        for (int n = 0; n < AN; ++n) {
          int gc = col0 + wc * (BN / 2) + n * 16 + cc;
          float w1v = (gc < FSZ) ? w1[gc] : 0.f;
          #pragma unroll
          for (int r = 0; r < 4; ++r) {
            int gr = row0 + wr * (BM / 2) + m * 16 + cr + r;
            float xv = bf2f((unsigned short)Xb[(size_t)gr * 1024 + gc]);
            rsum[m * 4 + r] = fmaf(acc[m][n][r] + w1v, xv, rsum[m * 4 + r]);
          }
        }
      }
      #pragma unroll
      for (int mask = 1; mask < 16; mask <<= 1)
        #pragma unroll
        for (int i = 0; i < AM * 4; ++i)
          rsum[i] += __shfl_xor(rsum[i], mask, 64);
      if (cc == 0) {
        #pragma unroll
        for (int m = 0; m < AM; ++m)
          #pragma unroll
          for (int r = 0; r < 4; ++r)
            pbuf[wc][wr * (BM / 2) + m * 16 + cr + r] = rsum[m * 4 + r];
      }
      __syncthreads();
      if (tid < BM)
        partial[(size_t)(row0 + tid) * 8 + blockIdx.x] = pbuf[0][tid] + pbuf[1][tid];
    } else {
      // h0 = relu(X@W0 + B0), bf16, stride 1024
      #pragma unroll
      for (int m = 0; m < AM; ++m) {
        #pragma unroll
        for (int n = 0; n < AN; ++n) {
          int gc = col0 - 1024 + wc * (BN / 2) + n * 16 + cc;
          float bv = bias[gc];
          #pragma unroll
          for (int r = 0; r < 4; ++r) {
            int gr = row0 + wr * (BM / 2) + m * 16 + cr + r;
            float v = fmaxf(acc[m][n][r] + bv, 0.f);
            ((short*)Cout)[(size_t)gr * 1024 + gc] = f2bf(v);
          }
        }
      }
    }
  } else if (EPI == 1) {
    #pragma unroll
    for (int m = 0; m < AM; ++m) {
      #pragma unroll
      for (int n = 0; n < AN; ++n) {
        int gc = col0 + wc * (BN / 2) + n * 16 + cc;
        float bv = bias[gc];
        #pragma unroll
        for (int r = 0; r < 4; ++r) {
          int gr = row0 + wr * (BM / 2) + m * 16 + cr + r;
          float v = fmaxf(acc[m][n][r] + bv, 0.f);
          ((short*)Cout)[(size_t)gr * N + gc] = f2bf(v);
        }
      }
    }
  } else {
    // EPI 3: out[r] = sum_c relu(acc+bias[c])*oW[c] + sum_8 part[r] + c1 + c2
    float rsum[AM * 4];
    #pragma unroll
    for (int i = 0; i < AM * 4; ++i) rsum[i] = 0.f;
    #pragma unroll
    for (int m = 0; m < AM; ++m) {
      #pragma unroll
      for (int n = 0; n < AN; ++n) {
        int gc = col0 + wc * (BN / 2) + n * 16 + cc;
        float bv = bias[gc];
        float ow = w1[gc];
        #pragma unroll
        for (int r = 0; r < 4; ++r) {
          float v = fmaxf(acc[m][n][r] + bv, 0.f);
          rsum[m * 4 + r] = fmaf(v, ow, rsum[m * 4 + r]);
        }
      }
    }
    #pragma unroll
    for (int mask = 1; mask < 16; mask <<= 1)
      #pragma unroll
      for (int i = 0; i < AM * 4; ++i)
        rsum[i] += __shfl_xor(rsum[i], mask, 64);
    if (cc == 0) {
      #pragma unroll
      for (int m = 0; m < AM; ++m)
        #pragma unroll
        for (int r = 0; r < 4; ++r)
          pbuf[wc][wr * (BM / 2) + m * 16 + cr + r] = rsum[m * 4 + r];
    }
    __syncthreads();
    if (tid < BM) {
      int gr = row0 + tid;
      const float4* pp = (const float4*)(partial + (size_t)gr * 8);
      float4 u = pp[0], v = pp[1];
      ((float*)Cout)[gr] = pbuf[0][tid] + pbuf[1][tid]
          + u.x + u.y + u.z + u.w + v.x + v.y + v.z + v.w + c1[0] + c2[0];
    }
  }
}

// ---------------------------------------------------------------------------
extern "C" void kernel_launch(void* const* d_in, const int* in_sizes, int n_in,
                              void* d_out, int out_size, void* d_ws, size_t ws_size,
                              hipStream_t stream) {
  const float* X   = (const float*)d_in[0];
  const float* w1  = (const float*)d_in[1];
  const float* bsc = (const float*)d_in[2];
  const float* nfk = (const float*)d_in[3];
  const int*   f2f = (const int*)d_in[4];
  const float* W0  = (const float*)d_in[5];
  const float* B0  = (const float*)d_in[6];
  const float* W1  = (const float*)d_in[7];
  const float* B1  = (const float*)d_in[8];
  const float* W2  = (const float*)d_in[9];
  const float* B2  = (const float*)d_in[10];
  const float* oW  = (const float*)d_in[11];
  const float* oB  = (const float*)d_in[12];
  float* out = (float*)d_out;

  char* ws = (char*)d_ws;
  short* Xb   = (short*)(ws);                 // 8,388,608
  short* B12  = (short*)(ws + 8388608);       // 4,194,304 (Mt 0..1023, Wt0 1024..2047)
  short* Wt1  = (short*)(ws + 12582912);      // 1,048,576
  short* Wt2  = (short*)(ws + 13631488);      //   262,144
  float* part = (float*)(ws + 13893632);      //   131,072 (4096 x 8)
  short* h0   = (short*)(ws + 14680064);      // 8,388,608
  short* h1   = (short*)(ws + 23068672);      // 4,194,304  -> total 27,262,976 B

  // 1) prep
  prep_kernel<<<6784, 256, 0, stream>>>(X, nfk, f2f, W0, W1, W2,
                                        Xb, B12, Wt1, Wt2);
  // 2) fused [T-partials | h0] GEMM: N=2048, K=1024 (tri-skip bx<8)
  gemm_mfma<128, 128, 0><<<dim3(16, 32), 256, 0, stream>>>(
      Xb, B12, B0, h0, 2048, 1024, Xb, w1, part, nullptr, nullptr);
  // 3) h1 = relu(h0 @ W1 + B1): N=512, K=1024, 64x64 tiles (512 blocks)
  gemm_mfma<64, 64, 1><<<dim3(8, 64), 256, 0, stream>>>(
      h0, Wt1, B1, h1, 512, 1024, nullptr, nullptr, nullptr, nullptr, nullptr);
  // 4) gemm4 + out-dot + finalize: N=BN=256, K=512 -> out[]
  gemm_mfma<32, 256, 3><<<dim3(1, 128), 256, 0, stream>>>(
      h1, Wt2, B2, out, 256, 512, nullptr, oW, part, bsc, oB);
}

// Round 6
// 77.886 us; speedup vs baseline: 9.0790x; 1.0254x over previous
//
#include <hip/hip_runtime.h>

// ---------------------------------------------------------------------------
// DeepFFM round 6: 4 launches.
//  1) prep     : X->bf16(pad), Mt build (LDS-cached nfk row), W0/W1/W2 -> bf16^T
//  2) gemm12   : [T-partials | h0] = Xb @ [Mt ; Wt0]^T  (N=2048 fused)
//                triangular K-skip on interaction half; partials from Xb(bf16)
//  3) gemm3    : h1 = relu(h0 @ W1 + B1)   (64x64 tiles, 512 blocks)
//  4) gemm4    : BN=256 (full N) + fused out-dot + finalize -> writes out[]
// GEMMs: bf16 MFMA 16x16x32, fp32 acc, DOUBLE-buffered LDS with
// prefetch-before-compute (T3 minimum 2-phase: stage(t+1) issued before
// compute(t), ONE barrier per K-tile -> loads overlap MFMA),
// XOR-swizzled LDS (linear dest + pre-swizzled global src + swizzled read).
// ---------------------------------------------------------------------------

#define BATCH   4096
#define FSZ     1000
#define NFIELDS 39
#define KDIM    40

typedef __attribute__((ext_vector_type(8))) short short8v;  // 8 x bf16
typedef __attribute__((ext_vector_type(4))) float f32x4;

__device__ __forceinline__ short f2bf(float f) {
  unsigned u = __builtin_bit_cast(unsigned, f);
  u += 0x7fff + ((u >> 16) & 1);   // RNE (finite data)
  return (short)(u >> 16);
}
__device__ __forceinline__ float bf2f(unsigned short h) {
  unsigned u = (unsigned)h << 16;
  return __builtin_bit_cast(float, u);
}

typedef const __attribute__((address_space(1))) unsigned int* gas_ptr;
typedef __attribute__((address_space(3))) unsigned int* las_ptr;
__device__ __forceinline__ void gload16(const void* g, void* l) {
  __builtin_amdgcn_global_load_lds((gas_ptr)g, (las_ptr)l, 16, 0, 0);
}

// ---------------------------------------------------------------------------
// prep mega-kernel: block ranges
//  [0,4096)     : Xb row conversion (1000 -> 1024 pad)
//  [4096,5120)  : Mt row n (B12 rows 0..1023), nfk[n,:,:] cached in LDS
//  [5120,6144)  : W0^T -> B12 rows 1024..2047
//  [6144,6656)  : W1^T -> Wt1
//  [6656,6784)  : W2^T -> Wt2
// ---------------------------------------------------------------------------
__device__ __forceinline__ void transp32(
    const float* __restrict__ in, short* __restrict__ out, int idx, int nx,
    int K_in, int N_in, int Kpad, float (*t)[33], int tid)
{
  int n0 = (idx % nx) * 32, k0 = (idx / nx) * 32;
  int tx = tid & 31, ty = tid >> 5;
  #pragma unroll
  for (int i = 0; i < 32; i += 8) {
    int k = k0 + ty + i, n = n0 + tx;
    t[ty + i][tx] = (k < K_in && n < N_in) ? in[(size_t)k * N_in + n] : 0.f;
  }
  __syncthreads();
  #pragma unroll
  for (int i = 0; i < 32; i += 8) {
    int n = n0 + ty + i, k = k0 + tx;
    if (n < N_in && k < Kpad) out[(size_t)n * Kpad + k] = f2bf(t[tx][ty + i]);
  }
}

__global__ __launch_bounds__(256) void prep_kernel(
    const float* __restrict__ X, const float* __restrict__ nfk,
    const int* __restrict__ f2f,
    const float* __restrict__ W0, const float* __restrict__ W1,
    const float* __restrict__ W2,
    short* __restrict__ Xb, short* __restrict__ B12,
    short* __restrict__ Wt1, short* __restrict__ Wt2)
{
  __shared__ float tbuf[32][33];
  __shared__ float C[NFIELDS * 44];  // Mt: nfk[n,:,:], stride 44 (16B-aligned)
  const int bid = blockIdx.x, tid = threadIdx.x;
  if (bid < 4096) {
    int k = tid * 4;
    short4 o = make_short4(0, 0, 0, 0);
    if (k < FSZ) {
      float4 v = *(const float4*)(X + (size_t)bid * FSZ + k);
      o = make_short4(f2bf(v.x), f2bf(v.y), f2bf(v.z), f2bf(v.w));
    }
    *(short4*)(Xb + (size_t)bid * 1024 + k) = o;
  } else if (bid < 5120) {
    int n = bid - 4096;
    if (n < FSZ) {
      for (int t = tid; t < NFIELDS * KDIM; t += 256)
        C[(t / KDIM) * 44 + (t % KDIM)] = nfk[(size_t)n * (NFIELDS * KDIM) + t];
    }
    __syncthreads();
    int fn = (n < FSZ) ? f2f[n] : 0;
    #pragma unroll
    for (int kk = 0; kk < 4; ++kk) {
      int k = kk * 256 + tid;
      float s = 0.f;
      if (n < FSZ && k < n) {
        int fk = f2f[k];
        const float4* p = (const float4*)(nfk + ((size_t)k * NFIELDS + fn) * KDIM);
        const float4* q = (const float4*)&C[fk * 44];
        #pragma unroll
        for (int t = 0; t < KDIM / 4; ++t) {
          float4 a = p[t], b = q[t];
          s += a.x * b.x + a.y * b.y + a.z * b.z + a.w * b.w;
        }
      }
      B12[(size_t)n * 1024 + k] = f2bf(s);
    }
  } else if (bid < 6144) {
    transp32(W0, B12 + 1024 * 1024, bid - 5120, 32, 1000, 1024, 1024, tbuf, tid);
  } else if (bid < 6656) {
    transp32(W1, Wt1, bid - 6144, 16, 1024, 512, 1024, tbuf, tid);
  } else {
    transp32(W2, Wt2, bid - 6656, 8, 512, 256, 512, tbuf, tid);
  }
}

// ---------------------------------------------------------------------------
// bf16 MFMA GEMM, double-buffered prefetch (T3 min). A: MxK; Bt: NxK (=B^T).
// 256 thr, 4 waves 2x2, wave tile (BM/2)x(BN/2), frags AM=BM/32, AN=BN/32.
// EPI 0: dual (bx<8: interaction+linear partials, tri-K-skip, Xb-based;
//        bx>=8: h0 bf16 relu, stride 1024)
// EPI 1: bf16 + bias + relu
// EPI 3: fused out-dot + finalize: out[r] = sum_c relu(acc+bias[c])*oW[c]
//        + sum_8 part[r] + b0 + outB      (requires BN == N)
// ---------------------------------------------------------------------------
template<int BM, int BN, int EPI>
__global__ __launch_bounds__(256) void gemm_mfma(
    const short* __restrict__ A, const short* __restrict__ Bt,
    const float* __restrict__ bias, void* __restrict__ Cout,
    int N, int K,
    const short* __restrict__ Xb, const float* __restrict__ w1,
    float* __restrict__ partial,
    const float* __restrict__ c1, const float* __restrict__ c2)
{
  constexpr int AM = BM / 32, AN = BN / 32;
  __shared__ __align__(16) short As[2][BM * 64];
  __shared__ __align__(16) short Bs[2][BN * 64];
  __shared__ float pbuf[2][BM];

  const int tid  = threadIdx.x;
  const int wid  = tid >> 6;
  const int lane = tid & 63;
  const int wr   = wid >> 1, wc = wid & 1;
  const int row0 = blockIdx.y * BM;
  const int col0 = blockIdx.x * BN;

  const int lr8   = lane >> 3;        // chunk-local row 0..7
  const int cbase = (lane & 7) * 16;  // byte col within 128B row

  f32x4 acc[AM][AN];
  #pragma unroll
  for (int m = 0; m < AM; ++m)
    #pragma unroll
    for (int n = 0; n < AN; ++n) acc[m][n] = (f32x4)(0.f);

  auto stage = [&](int p, int k0) {
    #pragma unroll
    for (int j = 0; j < BM / 32; ++j) {
      int i = j * 4 + wid;               // 1 KiB chunk = 8 rows
      int r = i * 8 + lr8;
      int cb = cbase ^ ((r & 7) << 4);   // pre-swizzled global source
      gload16((const char*)A + (((size_t)(row0 + r) * K + k0) << 1) + cb,
              (char*)&As[p][0] + i * 1024);
    }
    #pragma unroll
    for (int j = 0; j < BN / 32; ++j) {
      int i = j * 4 + wid;
      int r = i * 8 + lr8;
      int cb = cbase ^ ((r & 7) << 4);
      gload16((const char*)Bt + (((size_t)(col0 + r) * K + k0) << 1) + cb,
              (char*)&Bs[p][0] + i * 1024);
    }
  };

  auto compute = [&](int p) {
    #pragma unroll
    for (int kk = 0; kk < 2; ++kk) {
      const int cb = kk * 64 + (lane >> 4) * 16;
      short8v a[AM], b[AN];
      #pragma unroll
      for (int m = 0; m < AM; ++m) {
        int r = wr * (BM / 2) + m * 16 + (lane & 15);
        a[m] = *(const short8v*)((const char*)&As[p][0] + r * 128 + (cb ^ ((r & 7) << 4)));
      }
      #pragma unroll
      for (int n = 0; n < AN; ++n) {
        int r = wc * (BN / 2) + n * 16 + (lane & 15);
        b[n] = *(const short8v*)((const char*)&Bs[p][0] + r * 128 + (cb ^ ((r & 7) << 4)));
      }
      #pragma unroll
      for (int m = 0; m < AM; ++m)
        #pragma unroll
        for (int n = 0; n < AN; ++n)
          acc[m][n] = __builtin_amdgcn_mfma_f32_16x16x32_bf16(a[m], b[n], acc[m][n], 0, 0, 0);
    }
  };

  // Triangular K-skip: interaction cols [col0, col0+BN) only need k < col0+BN
  int nt = K >> 6;
  if (EPI == 0 && blockIdx.x < 8) {
    int need = ((int)blockIdx.x * 2) + 2;
    nt = nt < need ? nt : need;
  }

  // T3-minimum pipeline: stage(t+1) issued BEFORE compute(t); one barrier/tile.
  stage(0, 0);
  __syncthreads();                                   // loads of tile 0 visible
  for (int t = 0; t < nt; ++t) {
    if (t + 1 < nt) stage((t + 1) & 1, (t + 1) << 6);  // prefetch (in flight)
    compute(t & 1);                                     // overlaps with loads
    __syncthreads();                    // drain loads + compute-done handoff
  }

  const int cr = (lane >> 4) * 4;
  const int cc = lane & 15;

  if (EPI == 0) {
    if (blockIdx.x < 8) {
      // interaction + linear partials: sum_c (acc + w1[c]) * Xb[r][c]
      float rsum[AM * 4];
      #pragma unroll
      for (int i = 0; i < AM * 4; ++i) rsum[i] = 0.f;
      #pragma unroll
      for (int m = 0; m < AM; ++m) {
        #pragma unroll
        for (int n = 0; n < AN; ++n) {
          int gc = col0 + wc * (BN / 2) + n * 16 + cc;
          float w1v = (gc < FSZ) ? w1[gc] : 0.f;
          #pragma unroll
          for (int r = 0; r < 4; ++r) {
            int gr = row0 + wr * (BM / 2) + m * 16 + cr + r;
            float xv = bf2f((unsigned short)Xb[(size_t)gr * 1024 + gc]);
            rsum[m * 4 + r] = fmaf(acc[m][n][r] + w1v, xv, rsum[m * 4 + r]);
          }
        }
      }
      #pragma unroll
      for (int mask = 1; mask < 16; mask <<= 1)
        #pragma unroll
        for (int i = 0; i < AM * 4; ++i)
          rsum[i] += __shfl_xor(rsum[i], mask, 64);
      if (cc == 0) {
        #pragma unroll
        for (int m = 0; m < AM; ++m)
          #pragma unroll
          for (int r = 0; r < 4; ++r)
            pbuf[wc][wr * (BM / 2) + m * 16 + cr + r] = rsum[m * 4 + r];
      }
      __syncthreads();
      if (tid < BM)
        partial[(size_t)(row0 + tid) * 8 + blockIdx.x] = pbuf[0][tid] + pbuf[1][tid];
    } else {
      // h0 = relu(X@W0 + B0), bf16, stride 1024
      #pragma unroll
      for (int m = 0; m < AM; ++m) {
        #pragma unroll
        for (int n = 0; n < AN; ++n) {
          int gc = col0 - 1024 + wc * (BN / 2) + n * 16 + cc;
          float bv = bias[gc];
          #pragma unroll
          for (int r = 0; r < 4; ++r) {
            int gr = row0 + wr * (BM / 2) + m * 16 + cr + r;
            float v = fmaxf(acc[m][n][r] + bv, 0.f);
            ((short*)Cout)[(size_t)gr * 1024 + gc] = f2bf(v);
          }
        }
      }
    }
  } else if (EPI == 1) {
    #pragma unroll
    for (int m = 0; m < AM; ++m) {
      #pragma unroll
      for (int n = 0; n < AN; ++n) {
        int gc = col0 + wc * (BN / 2) + n * 16 + cc;
        float bv = bias[gc];
        #pragma unroll
        for (int r = 0; r < 4; ++r) {
          int gr = row0 + wr * (BM / 2) + m * 16 + cr + r;
          float v = fmaxf(acc[m][n][r] + bv, 0.f);
          ((short*)Cout)[(size_t)gr * N + gc] = f2bf(v);
        }
      }
    }
  } else {
    // EPI 3: out[r] = sum_c relu(acc+bias[c])*oW[c] + sum_8 part[r] + c1 + c2
    float rsum[AM * 4];
    #pragma unroll
    for (int i = 0; i < AM * 4; ++i) rsum[i] = 0.f;
    #pragma unroll
    for (int m = 0; m < AM; ++m) {
      #pragma unroll
      for (int n = 0; n < AN; ++n) {
        int gc = col0 + wc * (BN / 2) + n * 16 + cc;
        float bv = bias[gc];
        float ow = w1[gc];
        #pragma unroll
        for (int r = 0; r < 4; ++r) {
          float v = fmaxf(acc[m][n][r] + bv, 0.f);
          rsum[m * 4 + r] = fmaf(v, ow, rsum[m * 4 + r]);
        }
      }
    }
    #pragma unroll
    for (int mask = 1; mask < 16; mask <<= 1)
      #pragma unroll
      for (int i = 0; i < AM * 4; ++i)
        rsum[i] += __shfl_xor(rsum[i], mask, 64);
    if (cc == 0) {
      #pragma unroll
      for (int m = 0; m < AM; ++m)
        #pragma unroll
        for (int r = 0; r < 4; ++r)
          pbuf[wc][wr * (BM / 2) + m * 16 + cr + r] = rsum[m * 4 + r];
    }
    __syncthreads();
    if (tid < BM) {
      int gr = row0 + tid;
      const float4* pp = (const float4*)(partial + (size_t)gr * 8);
      float4 u = pp[0], v = pp[1];
      ((float*)Cout)[gr] = pbuf[0][tid] + pbuf[1][tid]
          + u.x + u.y + u.z + u.w + v.x + v.y + v.z + v.w + c1[0] + c2[0];
    }
  }
}

// ---------------------------------------------------------------------------
extern "C" void kernel_launch(void* const* d_in, const int* in_sizes, int n_in,
                              void* d_out, int out_size, void* d_ws, size_t ws_size,
                              hipStream_t stream) {
  const float* X   = (const float*)d_in[0];
  const float* w1  = (const float*)d_in[1];
  const float* bsc = (const float*)d_in[2];
  const float* nfk = (const float*)d_in[3];
  const int*   f2f = (const int*)d_in[4];
  const float* W0  = (const float*)d_in[5];
  const float* B0  = (const float*)d_in[6];
  const float* W1  = (const float*)d_in[7];
  const float* B1  = (const float*)d_in[8];
  const float* W2  = (const float*)d_in[9];
  const float* B2  = (const float*)d_in[10];
  const float* oW  = (const float*)d_in[11];
  const float* oB  = (const float*)d_in[12];
  float* out = (float*)d_out;

  char* ws = (char*)d_ws;
  short* Xb   = (short*)(ws);                 // 8,388,608
  short* B12  = (short*)(ws + 8388608);       // 4,194,304 (Mt 0..1023, Wt0 1024..2047)
  short* Wt1  = (short*)(ws + 12582912);      // 1,048,576
  short* Wt2  = (short*)(ws + 13631488);      //   262,144
  float* part = (float*)(ws + 13893632);      //   131,072 (4096 x 8)
  short* h0   = (short*)(ws + 14680064);      // 8,388,608
  short* h1   = (short*)(ws + 23068672);      // 4,194,304  -> total 27,262,976 B

  // 1) prep
  prep_kernel<<<6784, 256, 0, stream>>>(X, nfk, f2f, W0, W1, W2,
                                        Xb, B12, Wt1, Wt2);
  // 2) fused [T-partials | h0] GEMM: N=2048, K=1024 (tri-skip bx<8)
  gemm_mfma<128, 128, 0><<<dim3(16, 32), 256, 0, stream>>>(
      Xb, B12, B0, h0, 2048, 1024, Xb, w1, part, nullptr, nullptr);
  // 3) h1 = relu(h0 @ W1 + B1): N=512, K=1024, 64x64 tiles (512 blocks)
  gemm_mfma<64, 64, 1><<<dim3(8, 64), 256, 0, stream>>>(
      h0, Wt1, B1, h1, 512, 1024, nullptr, nullptr, nullptr, nullptr, nullptr);
  // 4) gemm4 + out-dot + finalize: N=BN=256, K=512 -> out[]
  gemm_mfma<32, 256, 3><<<dim3(1, 128), 256, 0, stream>>>(
      h1, Wt2, B2, out, 256, 512, nullptr, oW, part, bsc, oB);
}